// Round 9
// baseline (3508.952 us; speedup 1.0000x reference)
//
#include <hip/hip_runtime.h>
#include <stdint.h>

#define L_ 512
#define NBUF (L_ * L_)
#define T_ 64
#define NT_ 8
#define STR 70             // LDS row stride in words; 1-lane/cell patterns -> 71*lane+const -> <=2-way banks
#define INFV 3.0e38f
#define IDX(r, c) ((r) * STR + (c))

// ---------------------------------------------------------------------------
// pair_mask dtype probe (unchanged since r5 — verified working).
// ---------------------------------------------------------------------------
__global__ __launch_bounds__(1024) void fd_mask_probe(const unsigned int* __restrict__ pm,
                                                      int n32,
                                                      unsigned int* __restrict__ flags) {
    __shared__ unsigned int sf;
    if (threadIdx.x == 0) sf = 0u;
    __syncthreads();
    unsigned int local = 0;
    const int nscan = n32 < 65536 ? n32 : 65536;
    for (int idx = threadIdx.x; idx < nscan; idx += 1024) {
        const unsigned int w = pm[idx];
        const unsigned int h0 = w & 0xFFFFu, h1 = w >> 16;
        if (w > 1u) local |= 1u;
        if (w & 0xFEFEFEFEu) local |= 2u;
        if ((h0 != 0u && h0 != 0x3F80u) || (h1 != 0u && h1 != 0x3F80u)) local |= 4u;
        if (w == 0x3F803F80u || w == 0x00003F80u) local |= 8u;
        if ((h0 != 0u && h0 != 0x3C00u) || (h1 != 0u && h1 != 0x3C00u)) local |= 16u;
    }
    if (local) atomicOr(&sf, local);
    __syncthreads();
    if (threadIdx.x == 0) flags[0] = sf;
}

__device__ __forceinline__ int mask_mode(unsigned int f) {
    if (!(f & 1u)) return 0;
    if (!(f & 2u)) return 1;
    if (!(f & 4u)) return (f & 8u) ? 3 : 2;
    return (!(f & 16u)) ? 3 : 2;
}

__device__ __forceinline__ bool mask_bit(int mode, const unsigned int* pmW,
                                         const unsigned char* pm8,
                                         const unsigned short* pm16,
                                         const float* pmf, size_t gi) {
    if (mode == 0) return pmW[gi] != 0u;
    if (mode == 1) return pm8[gi] != 0;
    if (mode == 3) return pm16[gi] != 0;
    return pmf[gi] != 0.0f;
}

__device__ __forceinline__ void wave_sync_lds() {
    asm volatile("s_waitcnt lgkmcnt(0)" ::: "memory");
    __builtin_amdgcn_sched_barrier(0);
}

// lex (value, k) update where new k is known larger than all prior ks in acc
__device__ __forceinline__ void upd(float& v, int& k, float x, int kn) {
    if (x < v) { v = x; k = kn; }
}
// lex merge of two (v,k) candidates (first-occurrence argmin semantics)
__device__ __forceinline__ void lexm(float& v, int& k, float ov, int ok) {
    if (ov < v || (ov == v && ok < k)) { v = ov; k = ok; }
}

// ---------------------------------------------------------------------------
// Diagonal tiles (d=0): triangular 64x64 DP in LDS. Wave-synchronous:
// one wave, one lane per cell, no barriers/shuffles in the 63-step loop.
// ---------------------------------------------------------------------------
__global__ __launch_bounds__(256) void fd_diag(
    const float* __restrict__ e_pair, const float* __restrict__ e_unp,
    const unsigned int* __restrict__ pm, const unsigned int* __restrict__ flags,
    float* __restrict__ dp_ws, unsigned short* __restrict__ ptr_ws)
{
    const int b = blockIdx.x / NT_;
    const int I = blockIdx.x % NT_;
    const int t = threadIdx.x;
    const int r0 = I * T_;
    const float* ep = e_pair + (size_t)b * NBUF;
    float* dp = dp_ws + (size_t)b * NBUF;
    unsigned short* ptr = ptr_ws + (size_t)b * NBUF;
    const int mode = mask_mode(flags[0]);
    const unsigned int*   pmW  = pm + (size_t)b * NBUF;
    const unsigned char*  pm8  = ((const unsigned char*) pm) + (size_t)b * NBUF;
    const unsigned short* pm16 = ((const unsigned short*)pm) + (size_t)b * NBUF;
    const float*          pmf  = ((const float*)         pm) + (size_t)b * NBUF;

    __shared__ float Ct[T_ * STR];
    __shared__ float epl[T_ * STR];
    __shared__ unsigned char mkb[T_ * STR];
    __shared__ unsigned short bp[T_ * STR];
    __shared__ float eu[T_];

    for (int e = t; e < T_ * T_; e += 256) {
        const int r = e >> 6, c = e & 63;
        const size_t gi = (size_t)(r0 + r) * L_ + r0 + c;
        epl[IDX(r, c)] = ep[gi];
        mkb[IDX(r, c)] = mask_bit(mode, pmW, pm8, pm16, pmf, gi) ? 1 : 0;
    }
    if (t < T_) eu[t] = e_unp[(size_t)b * L_ + r0 + t];
    __syncthreads();

    if (t < 64) {
        const int c = t;
        Ct[IDX(c, c)] = eu[c];
        wave_sync_lds();
        for (int m = 1; m < T_; ++m) {
            if (c < T_ - m) {
                const int ti = c, tj = c + m;
                float v0 = INFV, v1 = INFV, v2 = INFV, v3 = INFV;
                int   k0 = 0,    k1 = 0,    k2 = 0,    k3 = 0;
                int n = ti;
                for (; n + 4 <= tj; n += 4) {
                    upd(v0, k0, Ct[IDX(ti, n + 0)] + Ct[IDX(n + 1, tj)], n + 0);
                    upd(v1, k1, Ct[IDX(ti, n + 1)] + Ct[IDX(n + 2, tj)], n + 1);
                    upd(v2, k2, Ct[IDX(ti, n + 2)] + Ct[IDX(n + 3, tj)], n + 2);
                    upd(v3, k3, Ct[IDX(ti, n + 3)] + Ct[IDX(n + 4, tj)], n + 3);
                }
                for (; n < tj; ++n)
                    upd(v0, k0, Ct[IDX(ti, n)] + Ct[IDX(n + 1, tj)], n);
                lexm(v0, k0, v1, k1); lexm(v2, k2, v3, k3); lexm(v0, k0, v2, k2);
                const float c0 = Ct[IDX(ti + 1, tj)] + eu[ti];
                const float c1 = Ct[IDX(ti, tj - 1)] + eu[tj];
                const float inner = (m >= 2) ? Ct[IDX(ti + 1, tj - 1)] : 0.0f;
                const float c2 = inner + epl[IDX(ti, tj)];
                const bool pok = mkb[IDX(ti, tj)] && (m > 4);
                float best = c0; int bv = 0;
                if (c1 < best)        { best = c1; bv = 1; }
                if (pok && c2 < best) { best = c2; bv = 2; }
                if (v0 < best)        { best = v0; bv = r0 + k0 + 3; }
                Ct[IDX(ti, tj)] = best;
                bp[IDX(ti, tj)] = (unsigned short)bv;
            }
            wave_sync_lds();
        }
    }
    __syncthreads();
    for (int e = t; e < T_ * T_; e += 256) {
        const int r = e >> 6, c = e & 63;
        if (c >= r) {
            const size_t gi = (size_t)(r0 + r) * L_ + r0 + c;
            dp[gi] = Ct[IDX(r, c)];
            if (c > r) ptr[gi] = bp[IDX(r, c)];
        }
    }
}

// ---------------------------------------------------------------------------
// Off-diagonal tile step (d>=1). Bulk min-plus over interior K blocks
// (256 threads, 4x4 reg tiles), then wave-synchronous 127-step intra-tile
// wavefront (one wave, 1 lane/cell, no barriers/shuffles).
// k ordering: left < rowB-term < bulk < right; lex merges on (v, abs k)
// == numpy first-occurrence argmin.
// ---------------------------------------------------------------------------
__global__ __launch_bounds__(256) void fd_step(
    const float* __restrict__ e_pair, const float* __restrict__ e_unp,
    const unsigned int* __restrict__ pm, const unsigned int* __restrict__ flags,
    float* __restrict__ dp_ws, unsigned short* __restrict__ ptr_ws,
    int d, int nI)
{
    const int b = blockIdx.x / nI;
    const int I = blockIdx.x % nI;
    const int J = I + d;
    const int t = threadIdx.x;
    const int r0 = I * T_, q0 = J * T_;
    const float* ep = e_pair + (size_t)b * NBUF;
    float* dp = dp_ws + (size_t)b * NBUF;
    unsigned short* ptr = ptr_ws + (size_t)b * NBUF;
    const int mode = mask_mode(flags[0]);
    const unsigned int*   pmW  = pm + (size_t)b * NBUF;
    const unsigned char*  pm8  = ((const unsigned char*) pm) + (size_t)b * NBUF;
    const unsigned short* pm16 = ((const unsigned short*)pm) + (size_t)b * NBUF;
    const float*          pmf  = ((const float*)         pm) + (size_t)b * NBUF;

    __shared__ float WA[T_ * STR];       // bulk: dp[i][k]; wavefront: tile (I,I)
    __shared__ float WB[T_ * STR];       // bulk: dp[k+1][j]; wavefront: tile (J,J)
    __shared__ float Ct[T_ * STR];       // tile being computed
    __shared__ float accv[T_ * STR];     // bulk lex-min value
    __shared__ unsigned short acck[T_ * STR];
    __shared__ float epl[T_ * STR];
    __shared__ unsigned char mkb[T_ * STR];
    __shared__ unsigned short bp[T_ * STR];
    __shared__ float euI[T_], euJ[T_], rowB[T_], colL[T_];
    __shared__ float cornerS;

    // ---- bulk: k in [(I+1)T, JT) over interior blocks K ----
    if (d >= 2) {
        float av[16]; int akr[16];
        const int ti0 = (t >> 4) * 4, tj0 = (t & 15) * 4;
#pragma unroll
        for (int q = 0; q < 16; ++q) { av[q] = INFV; akr[q] = 0; }
        for (int K = I + 1; K < J; ++K) {
            const int kb = K * T_;
            __syncthreads();
            for (int e = t; e < T_ * T_; e += 256) {
                const int r = e >> 6, c = e & 63;
                WA[IDX(r, c)] = dp[(size_t)(r0 + r) * L_ + kb + c];
                WB[IDX(r, c)] = dp[(size_t)(kb + 1 + r) * L_ + q0 + c];
            }
            __syncthreads();
            for (int kk = 0; kk < T_; ++kk) {
                float a[4], bb[4];
#pragma unroll
                for (int r = 0; r < 4; ++r) a[r] = WA[IDX(ti0 + r, kk)];
#pragma unroll
                for (int c = 0; c < 4; ++c) bb[c] = WB[IDX(kk, tj0 + c)];
                const int kg = kb + kk;
#pragma unroll
                for (int r = 0; r < 4; ++r)
#pragma unroll
                    for (int c = 0; c < 4; ++c) {
                        const float v = a[r] + bb[c];
                        const int q = r * 4 + c;
                        if (v < av[q]) { av[q] = v; akr[q] = kg; }
                    }
            }
        }
#pragma unroll
        for (int r = 0; r < 4; ++r)
#pragma unroll
            for (int c = 0; c < 4; ++c) {
                accv[IDX(ti0 + r, tj0 + c)] = av[r * 4 + c];
                acck[IDX(ti0 + r, tj0 + c)] = (unsigned short)akr[r * 4 + c];
            }
    }
    __syncthreads();

    // ---- stage wavefront inputs ----
    for (int e = t; e < T_ * T_; e += 256) {
        const int r = e >> 6, c = e & 63;
        WA[IDX(r, c)] = dp[(size_t)(r0 + r) * L_ + r0 + c];   // tile (I,I)
        WB[IDX(r, c)] = dp[(size_t)(q0 + r) * L_ + q0 + c];   // tile (J,J)
        const size_t gi = (size_t)(r0 + r) * L_ + q0 + c;
        epl[IDX(r, c)] = ep[gi];
        mkb[IDX(r, c)] = mask_bit(mode, pmW, pm8, pm16, pmf, gi) ? 1 : 0;
    }
    if (t < T_) {
        euI[t] = e_unp[(size_t)b * L_ + r0 + t];
        euJ[t] = e_unp[(size_t)b * L_ + q0 + t];
        rowB[t] = dp[(size_t)(r0 + T_) * L_ + q0 + t];   // dp[(I+1)T][j]
        colL[t] = dp[(size_t)(r0 + t) * L_ + q0 - 1];    // dp[i][JT-1]
    }
    if (t == 0) cornerS = (d >= 2) ? dp[(size_t)(r0 + T_) * L_ + q0 - 1] : 0.0f;
    __syncthreads();

    // ---- wave-synchronous intra-tile wavefront ----
    if (t < 64) {
        const int c = t;
        for (int m = -(T_ - 1); m <= T_ - 1; ++m) {
            const int am = m < 0 ? -m : m;
            if (c < T_ - am) {
                const int ti = (m < 0) ? c + am : c;
                const int tj = ti + m;
                const int span = d * T_ + m;
                float v0 = INFV, v1 = INFV, v2 = INFV, v3 = INFV;
                int   k0 = 0,    k1 = 0,    k2 = 0,    k3 = 0;
                // left: k = r0+n, n in [ti, T-1) via Ct column; then n = T-1 via rowB
                int n = ti;
                for (; n + 4 <= T_ - 1; n += 4) {
                    upd(v0, k0, WA[IDX(ti, n + 0)] + Ct[IDX(n + 1, tj)], r0 + n + 0);
                    upd(v1, k1, WA[IDX(ti, n + 1)] + Ct[IDX(n + 2, tj)], r0 + n + 1);
                    upd(v2, k2, WA[IDX(ti, n + 2)] + Ct[IDX(n + 3, tj)], r0 + n + 2);
                    upd(v3, k3, WA[IDX(ti, n + 3)] + Ct[IDX(n + 4, tj)], r0 + n + 3);
                }
                for (; n < T_ - 1; ++n)
                    upd(v0, k0, WA[IDX(ti, n)] + Ct[IDX(n + 1, tj)], r0 + n);
                upd(v0, k0, WA[IDX(ti, T_ - 1)] + rowB[tj], r0 + T_ - 1);
                // right: k = q0+n, n in [0, tj)  (all ks > left ks)
                n = 0;
                for (; n + 4 <= tj; n += 4) {
                    upd(v0, k0, Ct[IDX(ti, n + 0)] + WB[IDX(n + 1, tj)], q0 + n + 0);
                    upd(v1, k1, Ct[IDX(ti, n + 1)] + WB[IDX(n + 2, tj)], q0 + n + 1);
                    upd(v2, k2, Ct[IDX(ti, n + 2)] + WB[IDX(n + 3, tj)], q0 + n + 2);
                    upd(v3, k3, Ct[IDX(ti, n + 3)] + WB[IDX(n + 4, tj)], q0 + n + 3);
                }
                for (; n < tj; ++n)
                    upd(v0, k0, Ct[IDX(ti, n)] + WB[IDX(n + 1, tj)], q0 + n);
                lexm(v0, k0, v1, k1); lexm(v2, k2, v3, k3); lexm(v0, k0, v2, k2);
                if (d >= 2) lexm(v0, k0, accv[IDX(ti, tj)], acck[IDX(ti, tj)]);
                const float c0 = ((ti < T_ - 1) ? Ct[IDX(ti + 1, tj)] : rowB[tj]) + euI[ti];
                const float c1 = ((tj > 0) ? Ct[IDX(ti, tj - 1)] : colL[ti]) + euJ[tj];
                float inner;
                if (span == 1)        inner = 0.0f;
                else if (ti < T_ - 1) inner = (tj > 0) ? Ct[IDX(ti + 1, tj - 1)] : colL[ti + 1];
                else                  inner = (tj > 0) ? rowB[tj - 1] : cornerS;
                const float c2 = inner + epl[IDX(ti, tj)];
                const bool pok = mkb[IDX(ti, tj)] && (span > 4);
                float best = c0; int bv = 0;
                if (c1 < best)        { best = c1; bv = 1; }
                if (pok && c2 < best) { best = c2; bv = 2; }
                if (v0 < best)        { best = v0; bv = k0 + 3; }
                Ct[IDX(ti, tj)] = best;
                bp[IDX(ti, tj)] = (unsigned short)bv;
            }
            wave_sync_lds();
        }
    }
    __syncthreads();

    // ---- writeback ----
    for (int e = t; e < T_ * T_; e += 256) {
        const int r = e >> 6, c = e & 63;
        dp [(size_t)(r0 + r) * L_ + q0 + c] = Ct[IDX(r, c)];
        ptr[(size_t)(r0 + r) * L_ + q0 + c] = bp[IDX(r, c)];
    }
}

// ---------------------------------------------------------------------------
// Backtrace: warm this batch's 512KB ptr slab into the local XCD L2, then
// serial LIFO walk (t==0) with L2-hit latency.
// ---------------------------------------------------------------------------
__global__ __launch_bounds__(256) void fd_backtrace(
    const unsigned short* __restrict__ ptr_ws, int* __restrict__ out)
{
    const int b = blockIdx.x;
    const int t = threadIdx.x;
    const unsigned short* ptr = ptr_ws + (size_t)b * NBUF;
    int* res = out + (size_t)b * L_;
    __shared__ int sti[2 * L_], stj[2 * L_];

    const uint4* p4 = (const uint4*)ptr;
    unsigned int acc = 0;
    for (int idx = t; idx < NBUF / 8; idx += 256) {
        const uint4 v = p4[idx];
        acc += v.x ^ v.y ^ v.z ^ v.w;
    }
    asm volatile("" :: "v"(acc));
    for (int idx = t; idx < L_; idx += 256) res[idx] = -1;
    __syncthreads();

    if (t == 0) {
        int sp = 1; sti[0] = 0; stj[0] = L_ - 1;
        while (sp > 0) {
            --sp;
            const int i = sti[sp], j = stj[sp];
            if (i < j) {
                const int p = (int)ptr[(size_t)i * L_ + j];
                if (p == 0)      { sti[sp] = i + 1; stj[sp] = j;     ++sp; }
                else if (p == 1) { sti[sp] = i;     stj[sp] = j - 1; ++sp; }
                else if (p == 2) {
                    res[i] = j; res[j] = i;
                    if (i + 1 <= j - 1) { sti[sp] = i + 1; stj[sp] = j - 1; ++sp; }
                } else {
                    const int k = p - 3;
                    sti[sp] = i;     stj[sp] = k; ++sp;   // pushed first
                    sti[sp] = k + 1; stj[sp] = j; ++sp;   // popped first (matches ref)
                }
            }
        }
    }
}

extern "C" void kernel_launch(void* const* d_in, const int* in_sizes, int n_in,
                              void* d_out, int out_size, void* d_ws, size_t ws_size,
                              hipStream_t stream) {
    const float* e_pair = (const float*)d_in[0];
    const float* e_unp  = (const float*)d_in[1];
    const unsigned int* pm = (const unsigned int*)d_in[2];
    const int B = in_sizes[1] / L_;
    int* out = (int*)d_out;

    // ws layout: [flags: 256B] [dp: B*L*L f32] [ptr: B*L*L u16]
    unsigned int* flags = (unsigned int*)d_ws;
    float* dp_ws = (float*)((char*)d_ws + 256);
    unsigned short* ptr_ws = (unsigned short*)(dp_ws + (size_t)B * NBUF);

    const int n32 = in_sizes[2] / 4;
    fd_mask_probe<<<dim3(1), dim3(1024), 0, stream>>>(pm, n32, flags);
    fd_diag<<<dim3(B * NT_), dim3(256), 0, stream>>>(e_pair, e_unp, pm, flags,
                                                     dp_ws, ptr_ws);
    for (int d = 1; d < NT_; ++d) {
        const int nI = NT_ - d;
        fd_step<<<dim3(B * nI), dim3(256), 0, stream>>>(e_pair, e_unp, pm, flags,
                                                        dp_ws, ptr_ws, d, nI);
    }
    fd_backtrace<<<dim3(B), dim3(256), 0, stream>>>(ptr_ws, out);
}

// Round 10
// 2389.166 us; speedup vs baseline: 1.4687x; 1.4687x over previous
//
#include <hip/hip_runtime.h>
#include <stdint.h>

#define L_ 512
#define NBUF (L_ * L_)
#define T_ 64
#define NT_ 8
#define PAD 5              // stride 69: 69%32=5, gcd(5,32)=1 -> <=2-way banks (r8-verified)
#define STR (T_ + PAD)
#define INFV 3.0e38f
#define IDX(r, c) ((r) * STR + (c))

// ---------------------------------------------------------------------------
// pair_mask dtype probe (unchanged since r5 — verified working).
// ---------------------------------------------------------------------------
__global__ __launch_bounds__(1024) void fd_mask_probe(const unsigned int* __restrict__ pm,
                                                      int n32,
                                                      unsigned int* __restrict__ flags) {
    __shared__ unsigned int sf;
    if (threadIdx.x == 0) sf = 0u;
    __syncthreads();
    unsigned int local = 0;
    const int nscan = n32 < 65536 ? n32 : 65536;
    for (int idx = threadIdx.x; idx < nscan; idx += 1024) {
        const unsigned int w = pm[idx];
        const unsigned int h0 = w & 0xFFFFu, h1 = w >> 16;
        if (w > 1u) local |= 1u;
        if (w & 0xFEFEFEFEu) local |= 2u;
        if ((h0 != 0u && h0 != 0x3F80u) || (h1 != 0u && h1 != 0x3F80u)) local |= 4u;
        if (w == 0x3F803F80u || w == 0x00003F80u) local |= 8u;
        if ((h0 != 0u && h0 != 0x3C00u) || (h1 != 0u && h1 != 0x3C00u)) local |= 16u;
    }
    if (local) atomicOr(&sf, local);
    __syncthreads();
    if (threadIdx.x == 0) flags[0] = sf;
}

__device__ __forceinline__ int mask_mode(unsigned int f) {
    if (!(f & 1u)) return 0;
    if (!(f & 2u)) return 1;
    if (!(f & 4u)) return (f & 8u) ? 3 : 2;
    return (!(f & 16u)) ? 3 : 2;
}

__device__ __forceinline__ bool mask_bit(int mode, const unsigned int* pmW,
                                         const unsigned char* pm8,
                                         const unsigned short* pm16,
                                         const float* pmf, size_t gi) {
    if (mode == 0) return pmW[gi] != 0u;
    if (mode == 1) return pm8[gi] != 0;
    if (mode == 3) return pm16[gi] != 0;
    return pmf[gi] != 0.0f;
}

__device__ __forceinline__ void wave_sync_lds() {
    asm volatile("s_waitcnt lgkmcnt(0)" ::: "memory");
    __builtin_amdgcn_sched_barrier(0);
}

__device__ __forceinline__ void lexm(float& v, int& k, float ov, int ok) {
    if (ov < v || (ov == v && ok < k)) { v = ov; k = ok; }
}

// ---------------------------------------------------------------------------
// Diagonal tiles (d=0): triangular 64x64 DP in LDS — r8-verbatim (347-era,
// not a bottleneck). 4 lanes/cell, shuffle lex-(v,k) reduce.
// ---------------------------------------------------------------------------
__global__ __launch_bounds__(256) void fd_diag(
    const float* __restrict__ e_pair, const float* __restrict__ e_unp,
    const unsigned int* __restrict__ pm, const unsigned int* __restrict__ flags,
    float* __restrict__ dp_ws, unsigned short* __restrict__ ptr_ws)
{
    const int b = blockIdx.x / NT_;
    const int I = blockIdx.x % NT_;
    const int t = threadIdx.x;
    const int r0 = I * T_;
    const float* ep = e_pair + (size_t)b * NBUF;
    float* dp = dp_ws + (size_t)b * NBUF;
    unsigned short* ptr = ptr_ws + (size_t)b * NBUF;
    const int mode = mask_mode(flags[0]);
    const unsigned int*   pmW  = pm + (size_t)b * NBUF;
    const unsigned char*  pm8  = ((const unsigned char*) pm) + (size_t)b * NBUF;
    const unsigned short* pm16 = ((const unsigned short*)pm) + (size_t)b * NBUF;
    const float*          pmf  = ((const float*)         pm) + (size_t)b * NBUF;

    __shared__ float Ct[T_ * STR];
    __shared__ float epl[T_ * STR];
    __shared__ unsigned char mkb[T_ * STR];
    __shared__ unsigned short bp[T_ * STR];
    __shared__ float eu[T_];

    for (int e = t; e < T_ * T_; e += 256) {
        const int r = e >> 6, c = e & 63;
        const size_t gi = (size_t)(r0 + r) * L_ + r0 + c;
        epl[IDX(r, c)] = ep[gi];
        mkb[IDX(r, c)] = mask_bit(mode, pmW, pm8, pm16, pmf, gi) ? 1 : 0;
    }
    if (t < T_) eu[t] = e_unp[(size_t)b * L_ + r0 + t];
    __syncthreads();
    if (t < T_) Ct[IDX(t, t)] = eu[t];
    __syncthreads();

    const int cell = t >> 2, sub = t & 3;
    for (int m = 1; m < T_; ++m) {
        if (cell < T_ - m) {
            const int ti = cell, tj = cell + m;
            float pf_c0 = 0, pf_c1 = 0, pf_in = 0, pf_ep = 0; bool pok = false;
            if (sub == 0) {
                pf_c0 = Ct[IDX(ti + 1, tj)];
                pf_c1 = Ct[IDX(ti, tj - 1)];
                pf_in = (m >= 2) ? Ct[IDX(ti + 1, tj - 1)] : 0.0f;
                pf_ep = epl[IDX(ti, tj)];
                pok = mkb[IDX(ti, tj)] && (m > 4);
            }
            float mv = INFV; int km = 0;
            for (int tk = ti + sub; tk < tj; tk += 4) {
                const float v = Ct[IDX(ti, tk)] + Ct[IDX(tk + 1, tj)];
                if (v < mv) { mv = v; km = tk; }
            }
            for (int off = 1; off < 4; off <<= 1) {
                const float ov = __shfl_xor(mv, off, 4);
                const int   ok = __shfl_xor(km, off, 4);
                if (ov < mv || (ov == mv && ok < km)) { mv = ov; km = ok; }
            }
            if (sub == 0) {
                const float c0 = pf_c0 + eu[ti];
                const float c1 = pf_c1 + eu[tj];
                const float c2 = pf_in + pf_ep;
                float best = c0; int bv = 0;
                if (c1 < best)        { best = c1; bv = 1; }
                if (pok && c2 < best) { best = c2; bv = 2; }
                if (mv < best)        { best = mv; bv = r0 + km + 3; }
                Ct[IDX(ti, tj)] = best;
                bp[IDX(ti, tj)] = (unsigned short)bv;
            }
        }
        __syncthreads();
    }
    for (int e = t; e < T_ * T_; e += 256) {
        const int r = e >> 6, c = e & 63;
        if (c >= r) {
            const size_t gi = (size_t)(r0 + r) * L_ + r0 + c;
            dp[gi] = Ct[IDX(r, c)];
            if (c > r) ptr[gi] = bp[IDX(r, c)];
        }
    }
}

// ---------------------------------------------------------------------------
// Off-diagonal tile step (d>=1). r8 bulk + staging, then HIERARCHICAL
// intra-tile wavefront: 4x4 grid of 16x16 subtiles, 7 phases, <=4 subtiles
// per phase mapped to the block's 4 waves. Per subtile: parallel ext-partial
// (finalized-subtile k terms, lex-merged into accv) then a 31-step
// wave-synchronous micro-wavefront (no block barriers inside a phase).
// All scans ascending-k strict-<, merges lex-(v,abs k) == numpy argmin.
// ---------------------------------------------------------------------------
__global__ __launch_bounds__(256) void fd_step(
    const float* __restrict__ e_pair, const float* __restrict__ e_unp,
    const unsigned int* __restrict__ pm, const unsigned int* __restrict__ flags,
    float* __restrict__ dp_ws, unsigned short* __restrict__ ptr_ws,
    int d, int nI)
{
    const int b = blockIdx.x / nI;
    const int I = blockIdx.x % nI;
    const int J = I + d;
    const int t = threadIdx.x;
    const int r0 = I * T_, q0 = J * T_;
    const float* ep = e_pair + (size_t)b * NBUF;
    float* dp = dp_ws + (size_t)b * NBUF;
    unsigned short* ptr = ptr_ws + (size_t)b * NBUF;
    const int mode = mask_mode(flags[0]);
    const unsigned int*   pmW  = pm + (size_t)b * NBUF;
    const unsigned char*  pm8  = ((const unsigned char*) pm) + (size_t)b * NBUF;
    const unsigned short* pm16 = ((const unsigned short*)pm) + (size_t)b * NBUF;
    const float*          pmf  = ((const float*)         pm) + (size_t)b * NBUF;

    __shared__ float WA[T_ * STR];       // bulk: dp[i][k]; wavefront: tile (I,I)
    __shared__ float WB[T_ * STR];       // bulk: dp[k+1][j]; wavefront: tile (J,J)
    __shared__ float Ct[T_ * STR];       // tile being computed
    __shared__ float accv[T_ * STR];     // bulk+ext lex-min value
    __shared__ unsigned short acck[T_ * STR];
    __shared__ float epl[T_ * STR];
    __shared__ unsigned char mkb[T_ * STR];
    __shared__ unsigned short bp[T_ * STR];
    __shared__ float euI[T_], euJ[T_], rowB[T_], colL[T_];
    __shared__ float cornerS;

    // ---- bulk: k in [(I+1)T, JT) over interior blocks K (r8-verbatim) ----
    if (d >= 2) {
        float av[16]; int akr[16];
        const int ti0 = (t >> 4) * 4, tj0 = (t & 15) * 4;
#pragma unroll
        for (int q = 0; q < 16; ++q) { av[q] = INFV; akr[q] = 0; }
        for (int K = I + 1; K < J; ++K) {
            const int kb = K * T_;
            __syncthreads();
            for (int e = t; e < T_ * T_; e += 256) {
                const int r = e >> 6, c = e & 63;
                WA[IDX(r, c)] = dp[(size_t)(r0 + r) * L_ + kb + c];
                WB[IDX(r, c)] = dp[(size_t)(kb + 1 + r) * L_ + q0 + c];
            }
            __syncthreads();
            for (int kk = 0; kk < T_; ++kk) {
                float a[4], bb[4];
#pragma unroll
                for (int r = 0; r < 4; ++r) a[r] = WA[IDX(ti0 + r, kk)];
#pragma unroll
                for (int c = 0; c < 4; ++c) bb[c] = WB[IDX(kk, tj0 + c)];
                const int kg = kb + kk;
#pragma unroll
                for (int r = 0; r < 4; ++r)
#pragma unroll
                    for (int c = 0; c < 4; ++c) {
                        const float v = a[r] + bb[c];
                        const int q = r * 4 + c;
                        if (v < av[q]) { av[q] = v; akr[q] = kg; }
                    }
            }
        }
#pragma unroll
        for (int r = 0; r < 4; ++r)
#pragma unroll
            for (int c = 0; c < 4; ++c) {
                accv[IDX(ti0 + r, tj0 + c)] = av[r * 4 + c];
                acck[IDX(ti0 + r, tj0 + c)] = (unsigned short)akr[r * 4 + c];
            }
    } else {
        for (int e = t; e < T_ * T_; e += 256) {
            accv[IDX(e >> 6, e & 63)] = INFV;
            acck[IDX(e >> 6, e & 63)] = 0;
        }
    }
    __syncthreads();

    // ---- stage wavefront inputs (r8-verbatim) ----
    for (int e = t; e < T_ * T_; e += 256) {
        const int r = e >> 6, c = e & 63;
        WA[IDX(r, c)] = dp[(size_t)(r0 + r) * L_ + r0 + c];   // tile (I,I)
        WB[IDX(r, c)] = dp[(size_t)(q0 + r) * L_ + q0 + c];   // tile (J,J)
        const size_t gi = (size_t)(r0 + r) * L_ + q0 + c;
        epl[IDX(r, c)] = ep[gi];
        mkb[IDX(r, c)] = mask_bit(mode, pmW, pm8, pm16, pmf, gi) ? 1 : 0;
    }
    if (t < T_) {
        euI[t] = e_unp[(size_t)b * L_ + r0 + t];
        euJ[t] = e_unp[(size_t)b * L_ + q0 + t];
        rowB[t] = dp[(size_t)(r0 + T_) * L_ + q0 + t];
        colL[t] = dp[(size_t)(r0 + t) * L_ + q0 - 1];
    }
    if (t == 0) cornerS = (d >= 2) ? dp[(size_t)(r0 + T_) * L_ + q0 - 1] : 0.0f;
    __syncthreads();

    // ---- hierarchical wavefront: 7 subtile phases ----
    const int wave = t >> 6, lane = t & 63;
    for (int p = 0; p < 7; ++p) {
        const int D = p - 3;
        const int aD = D < 0 ? -D : D;
        const int cnt = 4 - aD;
        if (wave < cnt) {
            const int si = ((D > 0) ? (3 - D) : 3) - wave;
            const int sj = si + D;
            const int sb = 16 * si, sc = 16 * sj;

            // -- ext-partial: 4 cells per lane (row u, cols wq+4x) --
            {
                const int u = lane & 15, wq = lane >> 4;
                const int tie = sb + u;
                float ev0 = INFV, ev1 = INFV, ev2 = INFV, ev3 = INFV;
                int   ek0 = 0,    ek1 = 0,    ek2 = 0,    ek3 = 0;
                const int tj0 = sc + wq, tj1 = sc + wq + 4, tj2 = sc + wq + 8, tj3 = sc + wq + 12;
                for (int n = sb + 15; n <= 62; ++n) {        // ext-left (ascending)
                    const float a = WA[IDX(tie, n)];
                    const int nr = IDX(n + 1, 0);
                    float x;
                    x = a + Ct[nr + tj0]; if (x < ev0) { ev0 = x; ek0 = r0 + n; }
                    x = a + Ct[nr + tj1]; if (x < ev1) { ev1 = x; ek1 = r0 + n; }
                    x = a + Ct[nr + tj2]; if (x < ev2) { ev2 = x; ek2 = r0 + n; }
                    x = a + Ct[nr + tj3]; if (x < ev3) { ev3 = x; ek3 = r0 + n; }
                }
                {                                            // rowB term (k = r0+63)
                    const float a = WA[IDX(tie, 63)];
                    float x;
                    x = a + rowB[tj0]; if (x < ev0) { ev0 = x; ek0 = r0 + 63; }
                    x = a + rowB[tj1]; if (x < ev1) { ev1 = x; ek1 = r0 + 63; }
                    x = a + rowB[tj2]; if (x < ev2) { ev2 = x; ek2 = r0 + 63; }
                    x = a + rowB[tj3]; if (x < ev3) { ev3 = x; ek3 = r0 + 63; }
                }
                for (int n = 0; n < sc; ++n) {               // ext-right (ascending)
                    const float a = Ct[IDX(tie, n)];
                    const int nr = IDX(n + 1, 0);
                    float x;
                    x = a + WB[nr + tj0]; if (x < ev0) { ev0 = x; ek0 = q0 + n; }
                    x = a + WB[nr + tj1]; if (x < ev1) { ev1 = x; ek1 = q0 + n; }
                    x = a + WB[nr + tj2]; if (x < ev2) { ev2 = x; ek2 = q0 + n; }
                    x = a + WB[nr + tj3]; if (x < ev3) { ev3 = x; ek3 = q0 + n; }
                }
                // lex-merge into accv/acck (each cell owned by exactly one lane)
                float bv; int bk;
                bv = accv[IDX(tie, tj0)]; bk = acck[IDX(tie, tj0)];
                lexm(ev0, ek0, bv, bk); accv[IDX(tie, tj0)] = ev0; acck[IDX(tie, tj0)] = (unsigned short)ek0;
                bv = accv[IDX(tie, tj1)]; bk = acck[IDX(tie, tj1)];
                lexm(ev1, ek1, bv, bk); accv[IDX(tie, tj1)] = ev1; acck[IDX(tie, tj1)] = (unsigned short)ek1;
                bv = accv[IDX(tie, tj2)]; bk = acck[IDX(tie, tj2)];
                lexm(ev2, ek2, bv, bk); accv[IDX(tie, tj2)] = ev2; acck[IDX(tie, tj2)] = (unsigned short)ek2;
                bv = accv[IDX(tie, tj3)]; bk = acck[IDX(tie, tj3)];
                lexm(ev3, ek3, bv, bk); accv[IDX(tie, tj3)] = ev3; acck[IDX(tie, tj3)] = (unsigned short)ek3;
            }
            wave_sync_lds();

            // -- micro-wavefront: 31 steps, 16 cells x 4 lanes, wave-sync --
            const int cell = lane >> 2, sub = lane & 3;
            for (int mm = -15; mm <= 15; ++mm) {
                const int amm = mm < 0 ? -mm : mm;
                if (cell < 16 - amm) {
                    const int uu = (mm < 0) ? cell + amm : cell;
                    const int ww = uu + mm;
                    const int ti = sb + uu, tj = sc + ww;
                    const int span = d * T_ + (tj - ti);
                    float pf_c0 = 0, pf_c1 = 0, pf_in = 0, pf_ep = 0;
                    float bulk_v = INFV; int bulk_k = 0; bool pok = false;
                    if (sub == 0) {
                        pf_c0 = (ti < T_ - 1) ? Ct[IDX(ti + 1, tj)] : rowB[tj];
                        pf_c1 = (tj > 0) ? Ct[IDX(ti, tj - 1)] : colL[ti];
                        if (span == 1)        pf_in = 0.0f;
                        else if (ti < T_ - 1) pf_in = (tj > 0) ? Ct[IDX(ti + 1, tj - 1)] : colL[ti + 1];
                        else                  pf_in = (tj > 0) ? rowB[tj - 1] : cornerS;
                        pf_ep = epl[IDX(ti, tj)];
                        pok = mkb[IDX(ti, tj)] && (span > 4);
                        bulk_v = accv[IDX(ti, tj)]; bulk_k = acck[IDX(ti, tj)];
                    }
                    float mv = INFV; int km = 0;
                    // intra-left: n in [ti, sb+14]
                    for (int n = ti + sub; n <= sb + 14; n += 4) {
                        const float v = WA[IDX(ti, n)] + Ct[IDX(n + 1, tj)];
                        if (v < mv) { mv = v; km = r0 + n; }
                    }
                    // intra-right: n in [sc, tj)
                    for (int n = sc + sub; n < tj; n += 4) {
                        const float v = Ct[IDX(ti, n)] + WB[IDX(n + 1, tj)];
                        if (v < mv) { mv = v; km = q0 + n; }
                    }
                    for (int off = 1; off < 4; off <<= 1) {
                        const float ov = __shfl_xor(mv, off, 4);
                        const int   ok = __shfl_xor(km, off, 4);
                        if (ov < mv || (ov == mv && ok < km)) { mv = ov; km = ok; }
                    }
                    if (sub == 0) {
                        lexm(mv, km, bulk_v, bulk_k);
                        const float c0 = pf_c0 + euI[ti];
                        const float c1 = pf_c1 + euJ[tj];
                        const float c2 = pf_in + pf_ep;
                        float best = c0; int bv = 0;
                        if (c1 < best)        { best = c1; bv = 1; }
                        if (pok && c2 < best) { best = c2; bv = 2; }
                        if (mv < best)        { best = mv; bv = km + 3; }
                        Ct[IDX(ti, tj)] = best;
                        bp[IDX(ti, tj)] = (unsigned short)bv;
                    }
                }
                wave_sync_lds();
            }
        }
        __syncthreads();
    }

    // ---- writeback (r8-verbatim) ----
    for (int e = t; e < T_ * T_; e += 256) {
        const int r = e >> 6, c = e & 63;
        dp [(size_t)(r0 + r) * L_ + q0 + c] = Ct[IDX(r, c)];
        ptr[(size_t)(r0 + r) * L_ + q0 + c] = bp[IDX(r, c)];
    }
}

// ---------------------------------------------------------------------------
// Backtrace: L2 warm then serial LIFO walk (r8-verbatim).
// ---------------------------------------------------------------------------
__global__ __launch_bounds__(256) void fd_backtrace(
    const unsigned short* __restrict__ ptr_ws, int* __restrict__ out)
{
    const int b = blockIdx.x;
    const int t = threadIdx.x;
    const unsigned short* ptr = ptr_ws + (size_t)b * NBUF;
    int* res = out + (size_t)b * L_;
    __shared__ int sti[2 * L_], stj[2 * L_];

    const uint4* p4 = (const uint4*)ptr;
    unsigned int acc = 0;
    for (int idx = t; idx < NBUF / 8; idx += 256) {
        const uint4 v = p4[idx];
        acc += v.x ^ v.y ^ v.z ^ v.w;
    }
    asm volatile("" :: "v"(acc));
    for (int idx = t; idx < L_; idx += 256) res[idx] = -1;
    __syncthreads();

    if (t == 0) {
        int sp = 1; sti[0] = 0; stj[0] = L_ - 1;
        while (sp > 0) {
            --sp;
            const int i = sti[sp], j = stj[sp];
            if (i < j) {
                const int p = (int)ptr[(size_t)i * L_ + j];
                if (p == 0)      { sti[sp] = i + 1; stj[sp] = j;     ++sp; }
                else if (p == 1) { sti[sp] = i;     stj[sp] = j - 1; ++sp; }
                else if (p == 2) {
                    res[i] = j; res[j] = i;
                    if (i + 1 <= j - 1) { sti[sp] = i + 1; stj[sp] = j - 1; ++sp; }
                } else {
                    const int k = p - 3;
                    sti[sp] = i;     stj[sp] = k; ++sp;   // pushed first
                    sti[sp] = k + 1; stj[sp] = j; ++sp;   // popped first (matches ref)
                }
            }
        }
    }
}

extern "C" void kernel_launch(void* const* d_in, const int* in_sizes, int n_in,
                              void* d_out, int out_size, void* d_ws, size_t ws_size,
                              hipStream_t stream) {
    const float* e_pair = (const float*)d_in[0];
    const float* e_unp  = (const float*)d_in[1];
    const unsigned int* pm = (const unsigned int*)d_in[2];
    const int B = in_sizes[1] / L_;
    int* out = (int*)d_out;

    // ws layout: [flags: 256B] [dp: B*L*L f32] [ptr: B*L*L u16]
    unsigned int* flags = (unsigned int*)d_ws;
    float* dp_ws = (float*)((char*)d_ws + 256);
    unsigned short* ptr_ws = (unsigned short*)(dp_ws + (size_t)B * NBUF);

    const int n32 = in_sizes[2] / 4;
    fd_mask_probe<<<dim3(1), dim3(1024), 0, stream>>>(pm, n32, flags);
    fd_diag<<<dim3(B * NT_), dim3(256), 0, stream>>>(e_pair, e_unp, pm, flags,
                                                     dp_ws, ptr_ws);
    for (int d = 1; d < NT_; ++d) {
        const int nI = NT_ - d;
        fd_step<<<dim3(B * nI), dim3(256), 0, stream>>>(e_pair, e_unp, pm, flags,
                                                        dp_ws, ptr_ws, d, nI);
    }
    fd_backtrace<<<dim3(B), dim3(256), 0, stream>>>(ptr_ws, out);
}

// Round 11
// 2176.616 us; speedup vs baseline: 1.6121x; 1.0977x over previous
//
#include <hip/hip_runtime.h>
#include <stdint.h>

#define L_ 512
#define NBUF (L_ * L_)
#define T_ 64
#define NT_ 8
#define PAD 5              // stride 69: 69%32=5, gcd(5,32)=1 -> <=2-way banks (r8-verified)
#define STR (T_ + PAD)
#define INFV 3.0e38f
#define IDX(r, c) ((r) * STR + (c))

// ---------------------------------------------------------------------------
// pair_mask dtype probe (unchanged since r5 — verified working).
// ---------------------------------------------------------------------------
__global__ __launch_bounds__(1024) void fd_mask_probe(const unsigned int* __restrict__ pm,
                                                      int n32,
                                                      unsigned int* __restrict__ flags) {
    __shared__ unsigned int sf;
    if (threadIdx.x == 0) sf = 0u;
    __syncthreads();
    unsigned int local = 0;
    const int nscan = n32 < 65536 ? n32 : 65536;
    for (int idx = threadIdx.x; idx < nscan; idx += 1024) {
        const unsigned int w = pm[idx];
        const unsigned int h0 = w & 0xFFFFu, h1 = w >> 16;
        if (w > 1u) local |= 1u;
        if (w & 0xFEFEFEFEu) local |= 2u;
        if ((h0 != 0u && h0 != 0x3F80u) || (h1 != 0u && h1 != 0x3F80u)) local |= 4u;
        if (w == 0x3F803F80u || w == 0x00003F80u) local |= 8u;
        if ((h0 != 0u && h0 != 0x3C00u) || (h1 != 0u && h1 != 0x3C00u)) local |= 16u;
    }
    if (local) atomicOr(&sf, local);
    __syncthreads();
    if (threadIdx.x == 0) flags[0] = sf;
}

__device__ __forceinline__ int mask_mode(unsigned int f) {
    if (!(f & 1u)) return 0;
    if (!(f & 2u)) return 1;
    if (!(f & 4u)) return (f & 8u) ? 3 : 2;
    return (!(f & 16u)) ? 3 : 2;
}

__device__ __forceinline__ bool mask_bit(int mode, const unsigned int* pmW,
                                         const unsigned char* pm8,
                                         const unsigned short* pm16,
                                         const float* pmf, size_t gi) {
    if (mode == 0) return pmW[gi] != 0u;
    if (mode == 1) return pm8[gi] != 0;
    if (mode == 3) return pm16[gi] != 0;
    return pmf[gi] != 0.0f;
}

__device__ __forceinline__ void wave_sync_lds() {
    asm volatile("s_waitcnt lgkmcnt(0)" ::: "memory");
    __builtin_amdgcn_sched_barrier(0);
}

__device__ __forceinline__ void lexm(float& v, int& k, float ov, int ok) {
    if (ov < v || (ov == v && ok < k)) { v = ov; k = ok; }
}

// ---------------------------------------------------------------------------
// Diagonal tiles (d=0): triangular 64x64 DP in LDS. r8 structure; k-loop
// unrolled x4 so LDS loads batch under one waitcnt.
// ---------------------------------------------------------------------------
__global__ __launch_bounds__(256) void fd_diag(
    const float* __restrict__ e_pair, const float* __restrict__ e_unp,
    const unsigned int* __restrict__ pm, const unsigned int* __restrict__ flags,
    float* __restrict__ dp_ws, unsigned short* __restrict__ ptr_ws)
{
    const int b = blockIdx.x / NT_;
    const int I = blockIdx.x % NT_;
    const int t = threadIdx.x;
    const int r0 = I * T_;
    const float* ep = e_pair + (size_t)b * NBUF;
    float* dp = dp_ws + (size_t)b * NBUF;
    unsigned short* ptr = ptr_ws + (size_t)b * NBUF;
    const int mode = mask_mode(flags[0]);
    const unsigned int*   pmW  = pm + (size_t)b * NBUF;
    const unsigned char*  pm8  = ((const unsigned char*) pm) + (size_t)b * NBUF;
    const unsigned short* pm16 = ((const unsigned short*)pm) + (size_t)b * NBUF;
    const float*          pmf  = ((const float*)         pm) + (size_t)b * NBUF;

    __shared__ float Ct[T_ * STR];
    __shared__ float epl[T_ * STR];
    __shared__ unsigned char mkb[T_ * STR];
    __shared__ unsigned short bp[T_ * STR];
    __shared__ float eu[T_];

    for (int e = t; e < T_ * T_; e += 256) {
        const int r = e >> 6, c = e & 63;
        const size_t gi = (size_t)(r0 + r) * L_ + r0 + c;
        epl[IDX(r, c)] = ep[gi];
        mkb[IDX(r, c)] = mask_bit(mode, pmW, pm8, pm16, pmf, gi) ? 1 : 0;
    }
    if (t < T_) eu[t] = e_unp[(size_t)b * L_ + r0 + t];
    __syncthreads();
    if (t < T_) Ct[IDX(t, t)] = eu[t];
    __syncthreads();

    const int cell = t >> 2, sub = t & 3;
    for (int m = 1; m < T_; ++m) {
        if (cell < T_ - m) {
            const int ti = cell, tj = cell + m;
            float pf_c0 = 0, pf_c1 = 0, pf_in = 0, pf_ep = 0; bool pok = false;
            if (sub == 0) {
                pf_c0 = Ct[IDX(ti + 1, tj)];
                pf_c1 = Ct[IDX(ti, tj - 1)];
                pf_in = (m >= 2) ? Ct[IDX(ti + 1, tj - 1)] : 0.0f;
                pf_ep = epl[IDX(ti, tj)];
                pok = mkb[IDX(ti, tj)] && (m > 4);
            }
            float mv = INFV; int km = 0;
#pragma unroll 4
            for (int tk = ti + sub; tk < tj; tk += 4) {
                const float v = Ct[IDX(ti, tk)] + Ct[IDX(tk + 1, tj)];
                if (v < mv) { mv = v; km = tk; }
            }
            for (int off = 1; off < 4; off <<= 1) {
                const float ov = __shfl_xor(mv, off, 4);
                const int   ok = __shfl_xor(km, off, 4);
                if (ov < mv || (ov == mv && ok < km)) { mv = ov; km = ok; }
            }
            if (sub == 0) {
                const float c0 = pf_c0 + eu[ti];
                const float c1 = pf_c1 + eu[tj];
                const float c2 = pf_in + pf_ep;
                float best = c0; int bv = 0;
                if (c1 < best)        { best = c1; bv = 1; }
                if (pok && c2 < best) { best = c2; bv = 2; }
                if (mv < best)        { best = mv; bv = r0 + km + 3; }
                Ct[IDX(ti, tj)] = best;
                bp[IDX(ti, tj)] = (unsigned short)bv;
            }
        }
        __syncthreads();
    }
    for (int e = t; e < T_ * T_; e += 256) {
        const int r = e >> 6, c = e & 63;
        if (c >= r) {
            const size_t gi = (size_t)(r0 + r) * L_ + r0 + c;
            dp[gi] = Ct[IDX(r, c)];
            if (c > r) ptr[gi] = bp[IDX(r, c)];
        }
    }
}

// ---------------------------------------------------------------------------
// Off-diagonal tile step (d>=1). r10 structure (bulk + ext-partial +
// hierarchical 16x16 subtile wavefront), with the micro-step k-loops
// FIXED-UNROLLED (4 left + 4 right masked pair-loads -> one lgkmcnt wait)
// and the lane reduce done via 3 INDEPENDENT shfl gathers.
// All scans ascending-k strict-<, merges lex-(v,abs k) == numpy argmin.
// ---------------------------------------------------------------------------
__global__ __launch_bounds__(256) void fd_step(
    const float* __restrict__ e_pair, const float* __restrict__ e_unp,
    const unsigned int* __restrict__ pm, const unsigned int* __restrict__ flags,
    float* __restrict__ dp_ws, unsigned short* __restrict__ ptr_ws,
    int d, int nI)
{
    const int b = blockIdx.x / nI;
    const int I = blockIdx.x % nI;
    const int J = I + d;
    const int t = threadIdx.x;
    const int r0 = I * T_, q0 = J * T_;
    const float* ep = e_pair + (size_t)b * NBUF;
    float* dp = dp_ws + (size_t)b * NBUF;
    unsigned short* ptr = ptr_ws + (size_t)b * NBUF;
    const int mode = mask_mode(flags[0]);
    const unsigned int*   pmW  = pm + (size_t)b * NBUF;
    const unsigned char*  pm8  = ((const unsigned char*) pm) + (size_t)b * NBUF;
    const unsigned short* pm16 = ((const unsigned short*)pm) + (size_t)b * NBUF;
    const float*          pmf  = ((const float*)         pm) + (size_t)b * NBUF;

    __shared__ float WA[T_ * STR];       // bulk: dp[i][k]; wavefront: tile (I,I)
    __shared__ float WB[T_ * STR];       // bulk: dp[k+1][j]; wavefront: tile (J,J)
    __shared__ float Ct[T_ * STR];       // tile being computed
    __shared__ float accv[T_ * STR];     // bulk+ext lex-min value
    __shared__ unsigned short acck[T_ * STR];
    __shared__ float epl[T_ * STR];
    __shared__ unsigned char mkb[T_ * STR];
    __shared__ unsigned short bp[T_ * STR];
    __shared__ float euI[T_], euJ[T_], rowB[T_], colL[T_];
    __shared__ float cornerS;

    // ---- bulk: k in [(I+1)T, JT) over interior blocks K (r8-verbatim) ----
    if (d >= 2) {
        float av[16]; int akr[16];
        const int ti0 = (t >> 4) * 4, tj0 = (t & 15) * 4;
#pragma unroll
        for (int q = 0; q < 16; ++q) { av[q] = INFV; akr[q] = 0; }
        for (int K = I + 1; K < J; ++K) {
            const int kb = K * T_;
            __syncthreads();
            for (int e = t; e < T_ * T_; e += 256) {
                const int r = e >> 6, c = e & 63;
                WA[IDX(r, c)] = dp[(size_t)(r0 + r) * L_ + kb + c];
                WB[IDX(r, c)] = dp[(size_t)(kb + 1 + r) * L_ + q0 + c];
            }
            __syncthreads();
            for (int kk = 0; kk < T_; ++kk) {
                float a[4], bb[4];
#pragma unroll
                for (int r = 0; r < 4; ++r) a[r] = WA[IDX(ti0 + r, kk)];
#pragma unroll
                for (int c = 0; c < 4; ++c) bb[c] = WB[IDX(kk, tj0 + c)];
                const int kg = kb + kk;
#pragma unroll
                for (int r = 0; r < 4; ++r)
#pragma unroll
                    for (int c = 0; c < 4; ++c) {
                        const float v = a[r] + bb[c];
                        const int q = r * 4 + c;
                        if (v < av[q]) { av[q] = v; akr[q] = kg; }
                    }
            }
        }
#pragma unroll
        for (int r = 0; r < 4; ++r)
#pragma unroll
            for (int c = 0; c < 4; ++c) {
                accv[IDX(ti0 + r, tj0 + c)] = av[r * 4 + c];
                acck[IDX(ti0 + r, tj0 + c)] = (unsigned short)akr[r * 4 + c];
            }
    } else {
        for (int e = t; e < T_ * T_; e += 256) {
            accv[IDX(e >> 6, e & 63)] = INFV;
            acck[IDX(e >> 6, e & 63)] = 0;
        }
    }
    __syncthreads();

    // ---- stage wavefront inputs (r8-verbatim) ----
    for (int e = t; e < T_ * T_; e += 256) {
        const int r = e >> 6, c = e & 63;
        WA[IDX(r, c)] = dp[(size_t)(r0 + r) * L_ + r0 + c];   // tile (I,I)
        WB[IDX(r, c)] = dp[(size_t)(q0 + r) * L_ + q0 + c];   // tile (J,J)
        const size_t gi = (size_t)(r0 + r) * L_ + q0 + c;
        epl[IDX(r, c)] = ep[gi];
        mkb[IDX(r, c)] = mask_bit(mode, pmW, pm8, pm16, pmf, gi) ? 1 : 0;
    }
    if (t < T_) {
        euI[t] = e_unp[(size_t)b * L_ + r0 + t];
        euJ[t] = e_unp[(size_t)b * L_ + q0 + t];
        rowB[t] = dp[(size_t)(r0 + T_) * L_ + q0 + t];
        colL[t] = dp[(size_t)(r0 + t) * L_ + q0 - 1];
    }
    if (t == 0) cornerS = (d >= 2) ? dp[(size_t)(r0 + T_) * L_ + q0 - 1] : 0.0f;
    __syncthreads();

    // ---- hierarchical wavefront: 7 subtile phases ----
    const int wave = t >> 6, lane = t & 63;
    const int blane = lane & ~3;
    for (int p = 0; p < 7; ++p) {
        const int D = p - 3;
        const int aD = D < 0 ? -D : D;
        const int cnt = 4 - aD;
        if (wave < cnt) {
            const int si = ((D > 0) ? (3 - D) : 3) - wave;
            const int sj = si + D;
            const int sb = 16 * si, sc = 16 * sj;

            // -- ext-partial: 4 cells per lane (r10-verbatim) --
            {
                const int u = lane & 15, wq = lane >> 4;
                const int tie = sb + u;
                float ev0 = INFV, ev1 = INFV, ev2 = INFV, ev3 = INFV;
                int   ek0 = 0,    ek1 = 0,    ek2 = 0,    ek3 = 0;
                const int tj0 = sc + wq, tj1 = sc + wq + 4, tj2 = sc + wq + 8, tj3 = sc + wq + 12;
                for (int n = sb + 15; n <= 62; ++n) {        // ext-left (ascending)
                    const float a = WA[IDX(tie, n)];
                    const int nr = IDX(n + 1, 0);
                    float x;
                    x = a + Ct[nr + tj0]; if (x < ev0) { ev0 = x; ek0 = r0 + n; }
                    x = a + Ct[nr + tj1]; if (x < ev1) { ev1 = x; ek1 = r0 + n; }
                    x = a + Ct[nr + tj2]; if (x < ev2) { ev2 = x; ek2 = r0 + n; }
                    x = a + Ct[nr + tj3]; if (x < ev3) { ev3 = x; ek3 = r0 + n; }
                }
                {                                            // rowB term (k = r0+63)
                    const float a = WA[IDX(tie, 63)];
                    float x;
                    x = a + rowB[tj0]; if (x < ev0) { ev0 = x; ek0 = r0 + 63; }
                    x = a + rowB[tj1]; if (x < ev1) { ev1 = x; ek1 = r0 + 63; }
                    x = a + rowB[tj2]; if (x < ev2) { ev2 = x; ek2 = r0 + 63; }
                    x = a + rowB[tj3]; if (x < ev3) { ev3 = x; ek3 = r0 + 63; }
                }
                for (int n = 0; n < sc; ++n) {               // ext-right (ascending)
                    const float a = Ct[IDX(tie, n)];
                    const int nr = IDX(n + 1, 0);
                    float x;
                    x = a + WB[nr + tj0]; if (x < ev0) { ev0 = x; ek0 = q0 + n; }
                    x = a + WB[nr + tj1]; if (x < ev1) { ev1 = x; ek1 = q0 + n; }
                    x = a + WB[nr + tj2]; if (x < ev2) { ev2 = x; ek2 = q0 + n; }
                    x = a + WB[nr + tj3]; if (x < ev3) { ev3 = x; ek3 = q0 + n; }
                }
                float bv; int bk;
                bv = accv[IDX(tie, tj0)]; bk = acck[IDX(tie, tj0)];
                lexm(ev0, ek0, bv, bk); accv[IDX(tie, tj0)] = ev0; acck[IDX(tie, tj0)] = (unsigned short)ek0;
                bv = accv[IDX(tie, tj1)]; bk = acck[IDX(tie, tj1)];
                lexm(ev1, ek1, bv, bk); accv[IDX(tie, tj1)] = ev1; acck[IDX(tie, tj1)] = (unsigned short)ek1;
                bv = accv[IDX(tie, tj2)]; bk = acck[IDX(tie, tj2)];
                lexm(ev2, ek2, bv, bk); accv[IDX(tie, tj2)] = ev2; acck[IDX(tie, tj2)] = (unsigned short)ek2;
                bv = accv[IDX(tie, tj3)]; bk = acck[IDX(tie, tj3)];
                lexm(ev3, ek3, bv, bk); accv[IDX(tie, tj3)] = ev3; acck[IDX(tie, tj3)] = (unsigned short)ek3;
            }
            wave_sync_lds();

            // -- micro-wavefront: 31 steps; fixed-unroll masked loads --
            const int cell = lane >> 2, sub = lane & 3;
            for (int mm = -15; mm <= 15; ++mm) {
                const int amm = mm < 0 ? -mm : mm;
                if (cell < 16 - amm) {
                    const int uu = (mm < 0) ? cell + amm : cell;
                    const int ww = uu + mm;
                    const int ti = sb + uu, tj = sc + ww;
                    const int span = d * T_ + (tj - ti);
                    float pf_c0 = 0, pf_c1 = 0, pf_in = 0, pf_ep = 0;
                    float bulk_v = INFV; int bulk_k = 0; bool pok = false;
                    if (sub == 0) {
                        pf_c0 = (ti < T_ - 1) ? Ct[IDX(ti + 1, tj)] : rowB[tj];
                        pf_c1 = (tj > 0) ? Ct[IDX(ti, tj - 1)] : colL[ti];
                        if (span == 1)        pf_in = 0.0f;
                        else if (ti < T_ - 1) pf_in = (tj > 0) ? Ct[IDX(ti + 1, tj - 1)] : colL[ti + 1];
                        else                  pf_in = (tj > 0) ? rowB[tj - 1] : cornerS;
                        pf_ep = epl[IDX(ti, tj)];
                        pok = mkb[IDX(ti, tj)] && (span > 4);
                        bulk_v = accv[IDX(ti, tj)]; bulk_k = acck[IDX(ti, tj)];
                    }
                    float mv = INFV; int km = 0;
                    // intra-left: n = ti+sub+4u, valid while n <= sb+14 (trip <= 4)
                    {
                        const int n0 = ti + sub;
#pragma unroll
                        for (int u = 0; u < 4; ++u) {
                            const int n = n0 + 4 * u;
                            const bool ok = (n <= sb + 14);
                            const int nn = ok ? n : (sb + 14);       // clamp in-tile
                            const float x = WA[IDX(ti, nn)] + Ct[IDX(nn + 1, tj)];
                            const float xv = ok ? x : INFV;
                            if (xv < mv) { mv = xv; km = r0 + nn; }
                        }
                    }
                    // intra-right: n = sc+sub+4u, valid while n < tj (trip <= 4)
                    {
                        const int n1 = sc + sub;
#pragma unroll
                        for (int u = 0; u < 4; ++u) {
                            const int n = n1 + 4 * u;
                            const bool ok = (n < tj);
                            const int nn = ok ? n : sc;              // clamp in-tile
                            const float x = Ct[IDX(ti, nn)] + WB[IDX(nn + 1, tj)];
                            const float xv = ok ? x : INFV;
                            if (xv < mv) { mv = xv; km = q0 + nn; }
                        }
                    }
                    // 3 independent gathers (no dependent rounds)
                    const float g1 = __shfl(mv, blane + 1, 64); const int h1 = __shfl(km, blane + 1, 64);
                    const float g2 = __shfl(mv, blane + 2, 64); const int h2 = __shfl(km, blane + 2, 64);
                    const float g3 = __shfl(mv, blane + 3, 64); const int h3 = __shfl(km, blane + 3, 64);
                    if (sub == 0) {
                        lexm(mv, km, g1, h1);
                        lexm(mv, km, g2, h2);
                        lexm(mv, km, g3, h3);
                        lexm(mv, km, bulk_v, bulk_k);
                        const float c0 = pf_c0 + euI[ti];
                        const float c1 = pf_c1 + euJ[tj];
                        const float c2 = pf_in + pf_ep;
                        float best = c0; int bv = 0;
                        if (c1 < best)        { best = c1; bv = 1; }
                        if (pok && c2 < best) { best = c2; bv = 2; }
                        if (mv < best)        { best = mv; bv = km + 3; }
                        Ct[IDX(ti, tj)] = best;
                        bp[IDX(ti, tj)] = (unsigned short)bv;
                    }
                }
                wave_sync_lds();
            }
        }
        __syncthreads();
    }

    // ---- writeback (r8-verbatim) ----
    for (int e = t; e < T_ * T_; e += 256) {
        const int r = e >> 6, c = e & 63;
        dp [(size_t)(r0 + r) * L_ + q0 + c] = Ct[IDX(r, c)];
        ptr[(size_t)(r0 + r) * L_ + q0 + c] = bp[IDX(r, c)];
    }
}

// ---------------------------------------------------------------------------
// Backtrace: L2 warm then serial LIFO walk (r8-verbatim).
// ---------------------------------------------------------------------------
__global__ __launch_bounds__(256) void fd_backtrace(
    const unsigned short* __restrict__ ptr_ws, int* __restrict__ out)
{
    const int b = blockIdx.x;
    const int t = threadIdx.x;
    const unsigned short* ptr = ptr_ws + (size_t)b * NBUF;
    int* res = out + (size_t)b * L_;
    __shared__ int sti[2 * L_], stj[2 * L_];

    const uint4* p4 = (const uint4*)ptr;
    unsigned int acc = 0;
    for (int idx = t; idx < NBUF / 8; idx += 256) {
        const uint4 v = p4[idx];
        acc += v.x ^ v.y ^ v.z ^ v.w;
    }
    asm volatile("" :: "v"(acc));
    for (int idx = t; idx < L_; idx += 256) res[idx] = -1;
    __syncthreads();

    if (t == 0) {
        int sp = 1; sti[0] = 0; stj[0] = L_ - 1;
        while (sp > 0) {
            --sp;
            const int i = sti[sp], j = stj[sp];
            if (i < j) {
                const int p = (int)ptr[(size_t)i * L_ + j];
                if (p == 0)      { sti[sp] = i + 1; stj[sp] = j;     ++sp; }
                else if (p == 1) { sti[sp] = i;     stj[sp] = j - 1; ++sp; }
                else if (p == 2) {
                    res[i] = j; res[j] = i;
                    if (i + 1 <= j - 1) { sti[sp] = i + 1; stj[sp] = j - 1; ++sp; }
                } else {
                    const int k = p - 3;
                    sti[sp] = i;     stj[sp] = k; ++sp;   // pushed first
                    sti[sp] = k + 1; stj[sp] = j; ++sp;   // popped first (matches ref)
                }
            }
        }
    }
}

extern "C" void kernel_launch(void* const* d_in, const int* in_sizes, int n_in,
                              void* d_out, int out_size, void* d_ws, size_t ws_size,
                              hipStream_t stream) {
    const float* e_pair = (const float*)d_in[0];
    const float* e_unp  = (const float*)d_in[1];
    const unsigned int* pm = (const unsigned int*)d_in[2];
    const int B = in_sizes[1] / L_;
    int* out = (int*)d_out;

    // ws layout: [flags: 256B] [dp: B*L*L f32] [ptr: B*L*L u16]
    unsigned int* flags = (unsigned int*)d_ws;
    float* dp_ws = (float*)((char*)d_ws + 256);
    unsigned short* ptr_ws = (unsigned short*)(dp_ws + (size_t)B * NBUF);

    const int n32 = in_sizes[2] / 4;
    fd_mask_probe<<<dim3(1), dim3(1024), 0, stream>>>(pm, n32, flags);
    fd_diag<<<dim3(B * NT_), dim3(256), 0, stream>>>(e_pair, e_unp, pm, flags,
                                                     dp_ws, ptr_ws);
    for (int d = 1; d < NT_; ++d) {
        const int nI = NT_ - d;
        fd_step<<<dim3(B * nI), dim3(256), 0, stream>>>(e_pair, e_unp, pm, flags,
                                                        dp_ws, ptr_ws, d, nI);
    }
    fd_backtrace<<<dim3(B), dim3(256), 0, stream>>>(ptr_ws, out);
}

// Round 12
// 1944.251 us; speedup vs baseline: 1.8048x; 1.1195x over previous
//
#include <hip/hip_runtime.h>
#include <stdint.h>

#define L_ 512
#define NBUF (L_ * L_)
#define T_ 64
#define NT_ 8
#define PAD 5              // stride 69: 69%32=5, gcd(5,32)=1 -> <=2-way banks (r8-verified)
#define STR (T_ + PAD)
#define INFV 3.0e38f
#define IDX(r, c) ((r) * STR + (c))

// ---------------------------------------------------------------------------
// pair_mask dtype probe (unchanged since r5 — verified working).
// ---------------------------------------------------------------------------
__global__ __launch_bounds__(1024) void fd_mask_probe(const unsigned int* __restrict__ pm,
                                                      int n32,
                                                      unsigned int* __restrict__ flags) {
    __shared__ unsigned int sf;
    if (threadIdx.x == 0) sf = 0u;
    __syncthreads();
    unsigned int local = 0;
    const int nscan = n32 < 65536 ? n32 : 65536;
    for (int idx = threadIdx.x; idx < nscan; idx += 1024) {
        const unsigned int w = pm[idx];
        const unsigned int h0 = w & 0xFFFFu, h1 = w >> 16;
        if (w > 1u) local |= 1u;
        if (w & 0xFEFEFEFEu) local |= 2u;
        if ((h0 != 0u && h0 != 0x3F80u) || (h1 != 0u && h1 != 0x3F80u)) local |= 4u;
        if (w == 0x3F803F80u || w == 0x00003F80u) local |= 8u;
        if ((h0 != 0u && h0 != 0x3C00u) || (h1 != 0u && h1 != 0x3C00u)) local |= 16u;
    }
    if (local) atomicOr(&sf, local);
    __syncthreads();
    if (threadIdx.x == 0) flags[0] = sf;
}

__device__ __forceinline__ int mask_mode(unsigned int f) {
    if (!(f & 1u)) return 0;
    if (!(f & 2u)) return 1;
    if (!(f & 4u)) return (f & 8u) ? 3 : 2;
    return (!(f & 16u)) ? 3 : 2;
}

__device__ __forceinline__ bool mask_bit(int mode, const unsigned int* pmW,
                                         const unsigned char* pm8,
                                         const unsigned short* pm16,
                                         const float* pmf, size_t gi) {
    if (mode == 0) return pmW[gi] != 0u;
    if (mode == 1) return pm8[gi] != 0;
    if (mode == 3) return pm16[gi] != 0;
    return pmf[gi] != 0.0f;
}

__device__ __forceinline__ void wave_sync_lds() {
    asm volatile("s_waitcnt lgkmcnt(0)" ::: "memory");
    __builtin_amdgcn_sched_barrier(0);
}

__device__ __forceinline__ void lexm(float& v, int& k, float ov, int ok) {
    if (ov < v || (ov == v && ok < k)) { v = ov; k = ok; }
}

// DPP quad_perm cross-lane (VALU-speed, ~4cyc, no LDS/lgkmcnt).
// 0xB1 = quad_perm(1,0,3,2) = lane^1 ; 0x4E = quad_perm(2,3,0,1) = lane^2
template <int CTRL>
__device__ __forceinline__ float dpp_qp_f(float x) {
    return __int_as_float(__builtin_amdgcn_update_dpp(
        0, __float_as_int(x), CTRL, 0xF, 0xF, true));
}
template <int CTRL>
__device__ __forceinline__ int dpp_qp_i(int x) {
    return __builtin_amdgcn_update_dpp(0, x, CTRL, 0xF, 0xF, true);
}
// full 4-lane butterfly lex-(v,k) reduce: all lanes end with group min
__device__ __forceinline__ void quad_lexmin(float& mv, int& km) {
    float ov = dpp_qp_f<0xB1>(mv); int ok = dpp_qp_i<0xB1>(km);
    lexm(mv, km, ov, ok);
    ov = dpp_qp_f<0x4E>(mv); ok = dpp_qp_i<0x4E>(km);
    lexm(mv, km, ov, ok);
}

// ---------------------------------------------------------------------------
// Diagonal tiles (d=0): triangular 64x64 DP in LDS. r11 structure with the
// shuffle reduce replaced by DPP quad butterfly.
// ---------------------------------------------------------------------------
__global__ __launch_bounds__(256) void fd_diag(
    const float* __restrict__ e_pair, const float* __restrict__ e_unp,
    const unsigned int* __restrict__ pm, const unsigned int* __restrict__ flags,
    float* __restrict__ dp_ws, unsigned short* __restrict__ ptr_ws)
{
    const int b = blockIdx.x / NT_;
    const int I = blockIdx.x % NT_;
    const int t = threadIdx.x;
    const int r0 = I * T_;
    const float* ep = e_pair + (size_t)b * NBUF;
    float* dp = dp_ws + (size_t)b * NBUF;
    unsigned short* ptr = ptr_ws + (size_t)b * NBUF;
    const int mode = mask_mode(flags[0]);
    const unsigned int*   pmW  = pm + (size_t)b * NBUF;
    const unsigned char*  pm8  = ((const unsigned char*) pm) + (size_t)b * NBUF;
    const unsigned short* pm16 = ((const unsigned short*)pm) + (size_t)b * NBUF;
    const float*          pmf  = ((const float*)         pm) + (size_t)b * NBUF;

    __shared__ float Ct[T_ * STR];
    __shared__ float epl[T_ * STR];
    __shared__ unsigned char mkb[T_ * STR];
    __shared__ unsigned short bp[T_ * STR];
    __shared__ float eu[T_];

    for (int e = t; e < T_ * T_; e += 256) {
        const int r = e >> 6, c = e & 63;
        const size_t gi = (size_t)(r0 + r) * L_ + r0 + c;
        epl[IDX(r, c)] = ep[gi];
        mkb[IDX(r, c)] = mask_bit(mode, pmW, pm8, pm16, pmf, gi) ? 1 : 0;
    }
    if (t < T_) eu[t] = e_unp[(size_t)b * L_ + r0 + t];
    __syncthreads();
    if (t < T_) Ct[IDX(t, t)] = eu[t];
    __syncthreads();

    const int cell = t >> 2, sub = t & 3;
    for (int m = 1; m < T_; ++m) {
        if (cell < T_ - m) {
            const int ti = cell, tj = cell + m;
            float pf_c0 = 0, pf_c1 = 0, pf_in = 0, pf_ep = 0; bool pok = false;
            if (sub == 0) {
                pf_c0 = Ct[IDX(ti + 1, tj)];
                pf_c1 = Ct[IDX(ti, tj - 1)];
                pf_in = (m >= 2) ? Ct[IDX(ti + 1, tj - 1)] : 0.0f;
                pf_ep = epl[IDX(ti, tj)];
                pok = mkb[IDX(ti, tj)] && (m > 4);
            }
            float mv = INFV; int km = 0;
#pragma unroll 4
            for (int tk = ti + sub; tk < tj; tk += 4) {
                const float v = Ct[IDX(ti, tk)] + Ct[IDX(tk + 1, tj)];
                if (v < mv) { mv = v; km = tk; }
            }
            quad_lexmin(mv, km);
            if (sub == 0) {
                const float c0 = pf_c0 + eu[ti];
                const float c1 = pf_c1 + eu[tj];
                const float c2 = pf_in + pf_ep;
                float best = c0; int bv = 0;
                if (c1 < best)        { best = c1; bv = 1; }
                if (pok && c2 < best) { best = c2; bv = 2; }
                if (mv < best)        { best = mv; bv = r0 + km + 3; }
                Ct[IDX(ti, tj)] = best;
                bp[IDX(ti, tj)] = (unsigned short)bv;
            }
        }
        __syncthreads();
    }
    for (int e = t; e < T_ * T_; e += 256) {
        const int r = e >> 6, c = e & 63;
        if (c >= r) {
            const size_t gi = (size_t)(r0 + r) * L_ + r0 + c;
            dp[gi] = Ct[IDX(r, c)];
            if (c > r) ptr[gi] = bp[IDX(r, c)];
        }
    }
}

// ---------------------------------------------------------------------------
// Off-diagonal tile step, TEMPLATED on D (per-d rocprof symbols + constant
// folding). r11 structure; micro-step reduce via DPP quad butterfly.
// All scans ascending-k strict-<, merges lex-(v,abs k) == numpy argmin.
// ---------------------------------------------------------------------------
template <int D_>
__global__ __launch_bounds__(256) void fd_step(
    const float* __restrict__ e_pair, const float* __restrict__ e_unp,
    const unsigned int* __restrict__ pm, const unsigned int* __restrict__ flags,
    float* __restrict__ dp_ws, unsigned short* __restrict__ ptr_ws)
{
    constexpr int nI = NT_ - D_;
    const int b = blockIdx.x / nI;
    const int I = blockIdx.x % nI;
    const int J = I + D_;
    const int t = threadIdx.x;
    const int r0 = I * T_, q0 = J * T_;
    const float* ep = e_pair + (size_t)b * NBUF;
    float* dp = dp_ws + (size_t)b * NBUF;
    unsigned short* ptr = ptr_ws + (size_t)b * NBUF;
    const int mode = mask_mode(flags[0]);
    const unsigned int*   pmW  = pm + (size_t)b * NBUF;
    const unsigned char*  pm8  = ((const unsigned char*) pm) + (size_t)b * NBUF;
    const unsigned short* pm16 = ((const unsigned short*)pm) + (size_t)b * NBUF;
    const float*          pmf  = ((const float*)         pm) + (size_t)b * NBUF;

    __shared__ float WA[T_ * STR];       // bulk: dp[i][k]; wavefront: tile (I,I)
    __shared__ float WB[T_ * STR];       // bulk: dp[k+1][j]; wavefront: tile (J,J)
    __shared__ float Ct[T_ * STR];       // tile being computed
    __shared__ float accv[T_ * STR];     // bulk+ext lex-min value
    __shared__ unsigned short acck[T_ * STR];
    __shared__ float epl[T_ * STR];
    __shared__ unsigned char mkb[T_ * STR];
    __shared__ unsigned short bp[T_ * STR];
    __shared__ float euI[T_], euJ[T_], rowB[T_], colL[T_];
    __shared__ float cornerS;

    // ---- bulk: k in [(I+1)T, JT) over interior blocks K ----
    if constexpr (D_ >= 2) {
        float av[16]; int akr[16];
        const int ti0 = (t >> 4) * 4, tj0 = (t & 15) * 4;
#pragma unroll
        for (int q = 0; q < 16; ++q) { av[q] = INFV; akr[q] = 0; }
        for (int K = I + 1; K < J; ++K) {
            const int kb = K * T_;
            __syncthreads();
            for (int e = t; e < T_ * T_; e += 256) {
                const int r = e >> 6, c = e & 63;
                WA[IDX(r, c)] = dp[(size_t)(r0 + r) * L_ + kb + c];
                WB[IDX(r, c)] = dp[(size_t)(kb + 1 + r) * L_ + q0 + c];
            }
            __syncthreads();
            for (int kk = 0; kk < T_; ++kk) {
                float a[4], bb[4];
#pragma unroll
                for (int r = 0; r < 4; ++r) a[r] = WA[IDX(ti0 + r, kk)];
#pragma unroll
                for (int c = 0; c < 4; ++c) bb[c] = WB[IDX(kk, tj0 + c)];
                const int kg = kb + kk;
#pragma unroll
                for (int r = 0; r < 4; ++r)
#pragma unroll
                    for (int c = 0; c < 4; ++c) {
                        const float v = a[r] + bb[c];
                        const int q = r * 4 + c;
                        if (v < av[q]) { av[q] = v; akr[q] = kg; }
                    }
            }
        }
#pragma unroll
        for (int r = 0; r < 4; ++r)
#pragma unroll
            for (int c = 0; c < 4; ++c) {
                accv[IDX(ti0 + r, tj0 + c)] = av[r * 4 + c];
                acck[IDX(ti0 + r, tj0 + c)] = (unsigned short)akr[r * 4 + c];
            }
    }
    __syncthreads();

    // ---- stage wavefront inputs ----
    for (int e = t; e < T_ * T_; e += 256) {
        const int r = e >> 6, c = e & 63;
        WA[IDX(r, c)] = dp[(size_t)(r0 + r) * L_ + r0 + c];   // tile (I,I)
        WB[IDX(r, c)] = dp[(size_t)(q0 + r) * L_ + q0 + c];   // tile (J,J)
        const size_t gi = (size_t)(r0 + r) * L_ + q0 + c;
        epl[IDX(r, c)] = ep[gi];
        mkb[IDX(r, c)] = mask_bit(mode, pmW, pm8, pm16, pmf, gi) ? 1 : 0;
    }
    if (t < T_) {
        euI[t] = e_unp[(size_t)b * L_ + r0 + t];
        euJ[t] = e_unp[(size_t)b * L_ + q0 + t];
        rowB[t] = dp[(size_t)(r0 + T_) * L_ + q0 + t];
        colL[t] = dp[(size_t)(r0 + t) * L_ + q0 - 1];
    }
    if (t == 0) cornerS = (D_ >= 2) ? dp[(size_t)(r0 + T_) * L_ + q0 - 1] : 0.0f;
    __syncthreads();

    // ---- hierarchical wavefront: 7 subtile phases ----
    const int wave = t >> 6, lane = t & 63;
    for (int p = 0; p < 7; ++p) {
        const int D = p - 3;
        const int aD = D < 0 ? -D : D;
        const int cnt = 4 - aD;
        if (wave < cnt) {
            const int si = ((D > 0) ? (3 - D) : 3) - wave;
            const int sj = si + D;
            const int sb = 16 * si, sc = 16 * sj;

            // -- ext-partial: 4 cells per lane --
            {
                const int u = lane & 15, wq = lane >> 4;
                const int tie = sb + u;
                float ev0 = INFV, ev1 = INFV, ev2 = INFV, ev3 = INFV;
                int   ek0 = 0,    ek1 = 0,    ek2 = 0,    ek3 = 0;
                const int tj0 = sc + wq, tj1 = sc + wq + 4, tj2 = sc + wq + 8, tj3 = sc + wq + 12;
                for (int n = sb + 15; n <= 62; ++n) {        // ext-left (ascending)
                    const float a = WA[IDX(tie, n)];
                    const int nr = IDX(n + 1, 0);
                    float x;
                    x = a + Ct[nr + tj0]; if (x < ev0) { ev0 = x; ek0 = r0 + n; }
                    x = a + Ct[nr + tj1]; if (x < ev1) { ev1 = x; ek1 = r0 + n; }
                    x = a + Ct[nr + tj2]; if (x < ev2) { ev2 = x; ek2 = r0 + n; }
                    x = a + Ct[nr + tj3]; if (x < ev3) { ev3 = x; ek3 = r0 + n; }
                }
                {                                            // rowB term (k = r0+63)
                    const float a = WA[IDX(tie, 63)];
                    float x;
                    x = a + rowB[tj0]; if (x < ev0) { ev0 = x; ek0 = r0 + 63; }
                    x = a + rowB[tj1]; if (x < ev1) { ev1 = x; ek1 = r0 + 63; }
                    x = a + rowB[tj2]; if (x < ev2) { ev2 = x; ek2 = r0 + 63; }
                    x = a + rowB[tj3]; if (x < ev3) { ev3 = x; ek3 = r0 + 63; }
                }
                for (int n = 0; n < sc; ++n) {               // ext-right (ascending)
                    const float a = Ct[IDX(tie, n)];
                    const int nr = IDX(n + 1, 0);
                    float x;
                    x = a + WB[nr + tj0]; if (x < ev0) { ev0 = x; ek0 = q0 + n; }
                    x = a + WB[nr + tj1]; if (x < ev1) { ev1 = x; ek1 = q0 + n; }
                    x = a + WB[nr + tj2]; if (x < ev2) { ev2 = x; ek2 = q0 + n; }
                    x = a + WB[nr + tj3]; if (x < ev3) { ev3 = x; ek3 = q0 + n; }
                }
                if constexpr (D_ >= 2) {                     // merge bulk (older ks mid-range)
                    float bv; int bk;
                    bv = accv[IDX(tie, tj0)]; bk = acck[IDX(tie, tj0)]; lexm(ev0, ek0, bv, bk);
                    bv = accv[IDX(tie, tj1)]; bk = acck[IDX(tie, tj1)]; lexm(ev1, ek1, bv, bk);
                    bv = accv[IDX(tie, tj2)]; bk = acck[IDX(tie, tj2)]; lexm(ev2, ek2, bv, bk);
                    bv = accv[IDX(tie, tj3)]; bk = acck[IDX(tie, tj3)]; lexm(ev3, ek3, bv, bk);
                }
                accv[IDX(tie, tj0)] = ev0; acck[IDX(tie, tj0)] = (unsigned short)ek0;
                accv[IDX(tie, tj1)] = ev1; acck[IDX(tie, tj1)] = (unsigned short)ek1;
                accv[IDX(tie, tj2)] = ev2; acck[IDX(tie, tj2)] = (unsigned short)ek2;
                accv[IDX(tie, tj3)] = ev3; acck[IDX(tie, tj3)] = (unsigned short)ek3;
            }
            wave_sync_lds();

            // -- micro-wavefront: 31 steps; fixed-unroll loads + DPP reduce --
            const int cell = lane >> 2, sub = lane & 3;
            for (int mm = -15; mm <= 15; ++mm) {
                const int amm = mm < 0 ? -mm : mm;
                if (cell < 16 - amm) {
                    const int uu = (mm < 0) ? cell + amm : cell;
                    const int ww = uu + mm;
                    const int ti = sb + uu, tj = sc + ww;
                    const int span = D_ * T_ + (tj - ti);
                    float pf_c0 = 0, pf_c1 = 0, pf_in = 0, pf_ep = 0;
                    float bulk_v = INFV; int bulk_k = 0; bool pok = false;
                    if (sub == 0) {
                        pf_c0 = (ti < T_ - 1) ? Ct[IDX(ti + 1, tj)] : rowB[tj];
                        pf_c1 = (tj > 0) ? Ct[IDX(ti, tj - 1)] : colL[ti];
                        if (span == 1)        pf_in = 0.0f;
                        else if (ti < T_ - 1) pf_in = (tj > 0) ? Ct[IDX(ti + 1, tj - 1)] : colL[ti + 1];
                        else                  pf_in = (tj > 0) ? rowB[tj - 1] : cornerS;
                        pf_ep = epl[IDX(ti, tj)];
                        pok = mkb[IDX(ti, tj)] && (span > 4);
                        bulk_v = accv[IDX(ti, tj)]; bulk_k = acck[IDX(ti, tj)];
                    }
                    float mv = INFV; int km = 0;
                    // intra-left: n = ti+sub+4u, valid while n <= sb+14 (trip <= 4)
                    {
                        const int n0 = ti + sub;
#pragma unroll
                        for (int u = 0; u < 4; ++u) {
                            const int n = n0 + 4 * u;
                            const bool ok = (n <= sb + 14);
                            const int nn = ok ? n : (sb + 14);
                            const float x = WA[IDX(ti, nn)] + Ct[IDX(nn + 1, tj)];
                            const float xv = ok ? x : INFV;
                            if (xv < mv) { mv = xv; km = r0 + nn; }
                        }
                    }
                    // intra-right: n = sc+sub+4u, valid while n < tj (trip <= 4)
                    {
                        const int n1 = sc + sub;
#pragma unroll
                        for (int u = 0; u < 4; ++u) {
                            const int n = n1 + 4 * u;
                            const bool ok = (n < tj);
                            const int nn = ok ? n : sc;
                            const float x = Ct[IDX(ti, nn)] + WB[IDX(nn + 1, tj)];
                            const float xv = ok ? x : INFV;
                            if (xv < mv) { mv = xv; km = q0 + nn; }
                        }
                    }
                    quad_lexmin(mv, km);                     // VALU-speed DPP butterfly
                    if (sub == 0) {
                        lexm(mv, km, bulk_v, bulk_k);
                        const float c0 = pf_c0 + euI[ti];
                        const float c1 = pf_c1 + euJ[tj];
                        const float c2 = pf_in + pf_ep;
                        float best = c0; int bv = 0;
                        if (c1 < best)        { best = c1; bv = 1; }
                        if (pok && c2 < best) { best = c2; bv = 2; }
                        if (mv < best)        { best = mv; bv = km + 3; }
                        Ct[IDX(ti, tj)] = best;
                        bp[IDX(ti, tj)] = (unsigned short)bv;
                    }
                }
                wave_sync_lds();
            }
        }
        __syncthreads();
    }

    // ---- writeback ----
    for (int e = t; e < T_ * T_; e += 256) {
        const int r = e >> 6, c = e & 63;
        dp [(size_t)(r0 + r) * L_ + q0 + c] = Ct[IDX(r, c)];
        ptr[(size_t)(r0 + r) * L_ + q0 + c] = bp[IDX(r, c)];
    }
}

// ---------------------------------------------------------------------------
// Backtrace: L2 warm then serial LIFO walk (r8-verbatim).
// ---------------------------------------------------------------------------
__global__ __launch_bounds__(256) void fd_backtrace(
    const unsigned short* __restrict__ ptr_ws, int* __restrict__ out)
{
    const int b = blockIdx.x;
    const int t = threadIdx.x;
    const unsigned short* ptr = ptr_ws + (size_t)b * NBUF;
    int* res = out + (size_t)b * L_;
    __shared__ int sti[2 * L_], stj[2 * L_];

    const uint4* p4 = (const uint4*)ptr;
    unsigned int acc = 0;
    for (int idx = t; idx < NBUF / 8; idx += 256) {
        const uint4 v = p4[idx];
        acc += v.x ^ v.y ^ v.z ^ v.w;
    }
    asm volatile("" :: "v"(acc));
    for (int idx = t; idx < L_; idx += 256) res[idx] = -1;
    __syncthreads();

    if (t == 0) {
        int sp = 1; sti[0] = 0; stj[0] = L_ - 1;
        while (sp > 0) {
            --sp;
            const int i = sti[sp], j = stj[sp];
            if (i < j) {
                const int p = (int)ptr[(size_t)i * L_ + j];
                if (p == 0)      { sti[sp] = i + 1; stj[sp] = j;     ++sp; }
                else if (p == 1) { sti[sp] = i;     stj[sp] = j - 1; ++sp; }
                else if (p == 2) {
                    res[i] = j; res[j] = i;
                    if (i + 1 <= j - 1) { sti[sp] = i + 1; stj[sp] = j - 1; ++sp; }
                } else {
                    const int k = p - 3;
                    sti[sp] = i;     stj[sp] = k; ++sp;   // pushed first
                    sti[sp] = k + 1; stj[sp] = j; ++sp;   // popped first (matches ref)
                }
            }
        }
    }
}

extern "C" void kernel_launch(void* const* d_in, const int* in_sizes, int n_in,
                              void* d_out, int out_size, void* d_ws, size_t ws_size,
                              hipStream_t stream) {
    const float* e_pair = (const float*)d_in[0];
    const float* e_unp  = (const float*)d_in[1];
    const unsigned int* pm = (const unsigned int*)d_in[2];
    const int B = in_sizes[1] / L_;
    int* out = (int*)d_out;

    // ws layout: [flags: 256B] [dp: B*L*L f32] [ptr: B*L*L u16]
    unsigned int* flags = (unsigned int*)d_ws;
    float* dp_ws = (float*)((char*)d_ws + 256);
    unsigned short* ptr_ws = (unsigned short*)(dp_ws + (size_t)B * NBUF);

    const int n32 = in_sizes[2] / 4;
    fd_mask_probe<<<dim3(1), dim3(1024), 0, stream>>>(pm, n32, flags);
    fd_diag<<<dim3(B * NT_), dim3(256), 0, stream>>>(e_pair, e_unp, pm, flags,
                                                     dp_ws, ptr_ws);
    fd_step<1><<<dim3(B * 7), dim3(256), 0, stream>>>(e_pair, e_unp, pm, flags, dp_ws, ptr_ws);
    fd_step<2><<<dim3(B * 6), dim3(256), 0, stream>>>(e_pair, e_unp, pm, flags, dp_ws, ptr_ws);
    fd_step<3><<<dim3(B * 5), dim3(256), 0, stream>>>(e_pair, e_unp, pm, flags, dp_ws, ptr_ws);
    fd_step<4><<<dim3(B * 4), dim3(256), 0, stream>>>(e_pair, e_unp, pm, flags, dp_ws, ptr_ws);
    fd_step<5><<<dim3(B * 3), dim3(256), 0, stream>>>(e_pair, e_unp, pm, flags, dp_ws, ptr_ws);
    fd_step<6><<<dim3(B * 2), dim3(256), 0, stream>>>(e_pair, e_unp, pm, flags, dp_ws, ptr_ws);
    fd_step<7><<<dim3(B * 1), dim3(256), 0, stream>>>(e_pair, e_unp, pm, flags, dp_ws, ptr_ws);
    fd_backtrace<<<dim3(B), dim3(256), 0, stream>>>(ptr_ws, out);
}